// Round 3
// baseline (303.195 us; speedup 1.0000x reference)
//
#include <hip/hip_runtime.h>

typedef unsigned short ushort_t;
typedef unsigned int   uint_t;
typedef __attribute__((ext_vector_type(8))) short  short8;
typedef __attribute__((ext_vector_type(4))) float  float4v;
typedef __attribute__((ext_vector_type(4))) uint_t uint4v;
typedef __attribute__((ext_vector_type(2))) uint_t uint2v;

#define B_    16
#define CIN_  320
#define COUT_ 320
#define NLORA 50
#define R_    4
#define NCH   10                       // channel chunks of 32

// x_pad: [B][10][66][66][32] bf16 ; W_eff: [B][10][9][320][32] bf16
#define XCHUNK (66*66*32)              // 139,392 elems per (b,cc)
#define WCHUNK (9*COUT_*32)            // 92,160 elems per (b,cc)
#define XPAD_ELEMS ((size_t)B_ * NCH * XCHUNK)
#define WEFF_OFF   (XPAD_ELEMS * 2)    // bytes

__device__ __forceinline__ ushort_t bf16rne(float f) {
  uint_t u = __float_as_uint(f);
  u = (u + 0x7FFFu + ((u >> 16) & 1u)) >> 16;
  return (ushort_t)u;
}

__device__ __forceinline__ void gld16(const ushort_t* g, ushort_t* l) {
  __builtin_amdgcn_global_load_lds(
      (const __attribute__((address_space(1))) void*)g,
      (__attribute__((address_space(3))) void*)l,
      16, 0, 0);
}

// ---------------------------------------------------------------------------
// Kernel 1: x [B][C][H][W] fp32 -> x_pad [B][C/32][66][66][32] bf16.
// float4 global loads, LDS transpose (stride-65 rows: all access free of
// conflicts), uint2 (4-ch) stores. h==0 blocks also zero the border ring.
// ---------------------------------------------------------------------------
__global__ __launch_bounds__(256)
void pad_convert(const float* __restrict__ x, ushort_t* __restrict__ x_pad) {
  __shared__ float t[64][65];
  const int cc  = blockIdx.x;   // 64-ch group 0..4
  const int h   = blockIdx.y;   // 0..63
  const int b   = blockIdx.z;
  const int tid = threadIdx.x;
  #pragma unroll
  for (int it = 0; it < 4; ++it) {
    int idx = it * 256 + tid;               // 0..1023
    int cl = idx >> 4, w4 = (idx & 15) * 4;
    float4v v = *(const float4v*)(x +
        (((size_t)(b * CIN_ + cc * 64 + cl)) * 64 + h) * 64 + w4);
    t[cl][w4] = v[0]; t[cl][w4 + 1] = v[1];
    t[cl][w4 + 2] = v[2]; t[cl][w4 + 3] = v[3];
  }
  __syncthreads();
  #pragma unroll
  for (int it = 0; it < 4; ++it) {
    int j  = it * 256 + tid;                // 0..1023
    int cq = j & 15, wl = j >> 4;           // 4-ch group, col
    int cl = cq * 4;
    uint_t u0 = (uint_t)bf16rne(t[cl][wl])     | ((uint_t)bf16rne(t[cl + 1][wl]) << 16);
    uint_t u1 = (uint_t)bf16rne(t[cl + 2][wl]) | ((uint_t)bf16rne(t[cl + 3][wl]) << 16);
    int chunk = cc * 2 + (cl >> 5);
    uint2v u; u[0] = u0; u[1] = u1;
    *(uint2v*)(x_pad + (((size_t)(b * NCH + chunk) * 66 + (h + 1)) * 66 + (wl + 1)) * 32
               + (cl & 31)) = u;
  }
  if (h == 0) {
    #pragma unroll
    for (int s = 0; s < 2; ++s) {
      ushort_t* base = x_pad + (size_t)(b * NCH + cc * 2 + s) * XCHUNK;
      for (int g = tid; g < 528; g += 256) {            // rows 0 and 65
        int r = (g >= 264) ? 1 : 0;
        int g2 = g - r * 264;
        int col = g2 >> 2, qg = g2 & 3;
        *(uint4v*)(base + ((size_t)(r * 65) * 66 + col) * 32 + qg * 8) = (uint4v)0u;
      }
      for (int g = tid; g < 512; g += 256) {            // cols 0,65 rows 1..64
        int row = 1 + (g >> 3);
        int col = ((g >> 2) & 1) * 65;
        int qg  = g & 3;
        *(uint4v*)(base + ((size_t)row * 66 + col) * 32 + qg * 8) = (uint4v)0u;
      }
    }
  }
}

// ---------------------------------------------------------------------------
// Kernel 2: merged per-sample weights, COALESCED: lanes sweep flattened
// j = c*9+tap, so all 5 fp32 read streams are 4-B-stride wave loads (dense
// 256-B segments) instead of 36-B-stride gathers (36 lines/wave -> TA-bound).
//   W_eff[b][c/32][tap][o][c%32] = bf16(conv_w + act * sum_r up*down)
// ---------------------------------------------------------------------------
__global__ __launch_bounds__(320)
void merge_weights(const float* __restrict__ conv_w, const float* __restrict__ down_w,
                   const float* __restrict__ up_w,  const void* __restrict__ lora,
                   ushort_t* __restrict__ W_eff) {
  const int o = blockIdx.x;       // 0..319
  const int b = blockIdx.y;       // 0..15
  const int tid = threadIdx.x;    // 0..319

  const int* p32 = (const int*)lora;
  bool odd0 = true;
  #pragma unroll
  for (int i = 1; i < 16; i += 2) odd0 = odd0 && (p32[i] == 0);
  long long raw = odd0 ? ((const long long*)lora)[b] : (long long)p32[b];
  long long idx = (raw >= 0) ? (raw >> 2) : -(((-raw) + 3) >> 2);   // floor(raw/4)
  float act = (idx >= 0) ? 1.0f : 0.0f;                              // SCALE==1.0 folded
  int l = (int)(idx < 0 ? 0 : (idx > (NLORA - 1) ? (NLORA - 1) : idx));

  float up[R_];
  #pragma unroll
  for (int r = 0; r < R_; ++r)
    up[r] = up_w[((size_t)l * COUT_ + o) * R_ + r] * act;

  const float* cw = conv_w + (size_t)o * (CIN_ * 9);
  const float* dw = down_w + (size_t)l * (R_ * CIN_ * 9);
  #pragma unroll
  for (int it = 0; it < 9; ++it) {
    int j = it * 320 + tid;                 // 0..2879 = c*9 + tap
    float v = cw[j] + up[0] * dw[j] + up[1] * dw[2880 + j]
                    + up[2] * dw[5760 + j] + up[3] * dw[8640 + j];
    int c   = j / 9;                        // magic-mul
    int tap = j - c * 9;
    W_eff[(((size_t)(b * NCH + (c >> 5)) * 9 + tap) * COUT_ + o) * 32 + (c & 31)]
        = bf16rne(v);
  }
}

// ---------------------------------------------------------------------------
// Kernel 3: implicit-GEMM conv, bf16 MFMA 16x16x32, fp32 accumulate.
// Identical structure to round 2 (512 thr / 8 waves, 8x32x32 tile, exact
// vmcnt(5) pipeline, 2 blocks/CU) EXCEPT the LDS swizzle is now
// Q = q ^ ((ww>>1)&3)  (resp. (o>>1)&3), which is conflict-FREE per
// quarter-wave (8 distinct 4-bank groups x 2 lanes); round 2's linear layout
// was 8-way, round 1's q^(ww&3) was 4-way. Applied on BOTH the pre-swizzled
// gld16 global source and the ds_read address (rule: both sides or neither).
// ---------------------------------------------------------------------------
#define XG    1360                 // 10 rows * 34 cols * 4 quads
#define XGP   1408                 // padded to wave boundary
#define WG    1152                 // 9 taps * 32 o * 4 quads
#define TOTG  2560                 // XGP + WG  (= 5 * 512)
#define BUF_B (TOTG * 16)          // 40,960 B

__global__ __launch_bounds__(512, 4)
void conv_main(const ushort_t* __restrict__ x_pad, const ushort_t* __restrict__ W_eff,
               const float* __restrict__ conv_b, float* __restrict__ out) {
  __shared__ __align__(16) char smem[2 * BUF_B];   // 81,920 B

  const int tid = threadIdx.x;
  const int lin = blockIdx.x;                      // 0..2559
  const int wg  = (lin & 7) * 320 + (lin >> 3);    // XCD-bijective
  const int b   = wg / 160;
  const int rem = wg - b * 160;
  const int o0  = (rem >> 4) * 32;                 // o-chunk (outer: W reuse)
  const int hw  = rem & 15;
  const int h0  = (hw & 7) * 8;
  const int w0  = (hw >> 3) * 32;

  const int wv = tid >> 6;
  const int la = tid & 15;
  const int q  = (tid >> 4) & 3;

  // staging sources, pre-swizzled: granule (t,qq) fetches global quad
  // qq ^ ((pos>>1)&3) so the LINEAR LDS deposit realizes the swizzled layout.
  const ushort_t* psrc[5];
  int step[5];
  #pragma unroll
  for (int r = 0; r < 5; ++r) {
    int g = r * 512 + tid;
    if (g < XGP) {
      int gx = (g < XG) ? g : (XG - 1);            // tail dups land in LDS pad
      int qq = gx & 3, t = gx >> 2;
      int hh = t / 34, ww = t - hh * 34;
      int sq = qq ^ ((ww >> 1) & 3);
      psrc[r] = x_pad + (size_t)b * NCH * XCHUNK
              + (((h0 + hh) * 66 + (w0 + ww)) * 32 + sq * 8);
      step[r] = XCHUNK;
    } else {
      int gw = g - XGP;
      int qq = gw & 3, t2 = gw >> 2;
      int o = t2 & 31, tap = t2 >> 5;
      int sq = qq ^ ((o >> 1) & 3);
      psrc[r] = W_eff + (size_t)b * NCH * WCHUNK
              + ((tap * COUT_ + o0 + o) * 32 + sq * 8);
      step[r] = WCHUNK;
    }
  }

  float4v acc[2][2];
  #pragma unroll
  for (int i = 0; i < 2; ++i)
    #pragma unroll
    for (int n = 0; n < 2; ++n) acc[i][n] = (float4v)0.0f;

  auto STAGE = [&](int sel) {
    ushort_t* bufb = (ushort_t*)(smem + sel * BUF_B);
    #pragma unroll
    for (int r = 0; r < 5; ++r) {
      gld16(psrc[r], bufb + (r * 512 + wv * 64) * 8);
      psrc[r] += step[r];
    }
  };

  STAGE(0);                          // chunk 0 in flight
  int cur = 0;
  for (int t = 0; t < NCH; ++t) {
    asm volatile("" ::: "memory");
    __builtin_amdgcn_s_barrier();    // all waves done reading buf cur^1
    asm volatile("" ::: "memory");
    if (t < NCH - 1) STAGE(cur ^ 1);
    __builtin_amdgcn_sched_barrier(0);
    if (t < NCH - 1) asm volatile("s_waitcnt vmcnt(5)" ::: "memory");
    else             asm volatile("s_waitcnt vmcnt(0)" ::: "memory");
    __builtin_amdgcn_sched_barrier(0);
    __builtin_amdgcn_s_barrier();    // chunk t fully deposited (all waves)
    asm volatile("" ::: "memory");

    const ushort_t* xb = (const ushort_t*)(smem + cur * BUF_B);
    const ushort_t* wb = xb + XGP * 8;
    #pragma unroll
    for (int tap = 0; tap < 9; ++tap) {
      const int kh = tap / 3, kw = tap - kh * 3;
      const int ob0 = la, ob1 = 16 + la;
      short8 bf0 = *(const short8*)(wb + ((tap * 32 + ob0) * 4 + (q ^ ((ob0 >> 1) & 3))) * 8);
      short8 bf1 = *(const short8*)(wb + ((tap * 32 + ob1) * 4 + (q ^ ((ob1 >> 1) & 3))) * 8);
      const int hh = wv + kh;
      #pragma unroll
      for (int i = 0; i < 2; ++i) {
        int ww = i * 16 + la + kw;
        short8 af = *(const short8*)(xb + ((hh * 34 + ww) * 4 + (q ^ ((ww >> 1) & 3))) * 8);
        acc[i][0] = __builtin_amdgcn_mfma_f32_16x16x32_bf16(af, bf0, acc[i][0], 0, 0, 0);
        acc[i][1] = __builtin_amdgcn_mfma_f32_16x16x32_bf16(af, bf1, acc[i][1], 0, 0, 0);
      }
    }
    cur ^= 1;
  }

  // Epilogue: transpose C through LDS (stride 260 -> 2-way max, free),
  // add bias, coalesced float4 NCHW stores.
  __syncthreads();
  float* lc = (float*)smem;          // [32][260] fp32 = 33,280 B
  #pragma unroll
  for (int n = 0; n < 2; ++n) {
    const int n_loc = n * 16 + la;
    #pragma unroll
    for (int i = 0; i < 2; ++i)
      *(float4v*)(lc + n_loc * 260 + wv * 32 + i * 16 + q * 4) = acc[i][n];
  }
  __syncthreads();
  const size_t ob = ((size_t)(b * COUT_ + o0)) * 4096 + h0 * 64 + w0;
  for (int f = tid; f < 32 * 64; f += 512) {
    int n_loc = f >> 6;
    int m4 = (f & 63) * 4;
    int row = m4 >> 5, col = m4 & 31;
    float4v v = *(const float4v*)(lc + n_loc * 260 + m4);
    v += conv_b[o0 + n_loc];
    *(float4v*)(out + ob + (size_t)n_loc * 4096 + row * 64 + col) = v;
  }
}

// ---------------------------------------------------------------------------
extern "C" void kernel_launch(void* const* d_in, const int* in_sizes, int n_in,
                              void* d_out, int out_size, void* d_ws, size_t ws_size,
                              hipStream_t stream) {
  const float* x      = (const float*)d_in[0];
  const float* conv_w = (const float*)d_in[1];
  const float* conv_b = (const float*)d_in[2];
  const float* down_w = (const float*)d_in[3];
  const float* up_w   = (const float*)d_in[4];
  const void*  lora   = d_in[5];
  float* out = (float*)d_out;

  ushort_t* x_pad = (ushort_t*)d_ws;
  ushort_t* W_eff = (ushort_t*)((char*)d_ws + WEFF_OFF);

  pad_convert  <<<dim3(5, 64, 16), 256, 0, stream>>>(x, x_pad);
  merge_weights<<<dim3(320, 16),   320, 0, stream>>>(conv_w, down_w, up_w, lora, W_eff);
  conv_main    <<<dim3(2560),      512, 0, stream>>>(x_pad, W_eff, conv_b, out);
}

// Round 5
// 301.987 us; speedup vs baseline: 1.0040x; 1.0040x over previous
//
#include <hip/hip_runtime.h>

typedef unsigned short ushort_t;
typedef unsigned int   uint_t;
typedef __attribute__((ext_vector_type(8))) short  short8;
typedef __attribute__((ext_vector_type(4))) float  float4v;
typedef __attribute__((ext_vector_type(4))) uint_t uint4v;
typedef __attribute__((ext_vector_type(2))) uint_t uint2v;

#define B_    16
#define CIN_  320
#define COUT_ 320
#define NLORA 50
#define R_    4
#define NCH   10                       // channel chunks of 32

// x_pad: [B][10][66][66][32] bf16
#define XCHUNK (66*66*32)              // 139,392 elems per (b,cc)
// wb16:  [10][9][320][32] bf16 (batch-independent!)
#define WCHUNK (9*COUT_*32)            // 92,160 elems per chunk
// dwn_eff: [B][10][9][16][32] bf16 (r>=4 zero, act folded)
#define DCHUNK (9*16*32)               // 4,608 elems per (b,cc)
// down: [B][4][64][64] fp32

// workspace byte offsets
#define WB16_OFF  44605440ULL
#define DWNE_OFF  46448640ULL
#define DOWN_OFF  47923200ULL

__device__ __forceinline__ ushort_t bf16rne(float f) {
  uint_t u = __float_as_uint(f);
  u = (u + 0x7FFFu + ((u >> 16) & 1u)) >> 16;
  return (ushort_t)u;
}

__device__ __forceinline__ void gld16(const ushort_t* g, ushort_t* l) {
  __builtin_amdgcn_global_load_lds(
      (const __attribute__((address_space(1))) void*)g,
      (__attribute__((address_space(3))) void*)l,
      16, 0, 0);
}

// block-uniform lora index decode (int32/int64 sniff; reads first 64 B only)
__device__ __forceinline__ void lora_idx(const void* lora, int b, int* l_out,
                                         float* act_out) {
  const int* p32 = (const int*)lora;
  bool odd0 = true;
  #pragma unroll
  for (int i = 1; i < 16; i += 2) odd0 = odd0 && (p32[i] == 0);
  long long raw = odd0 ? ((const long long*)lora)[b] : (long long)p32[b];
  long long idx = (raw >= 0) ? (raw >> 2) : -(((-raw) + 3) >> 2);   // floor/4
  *act_out = (idx >= 0) ? 1.0f : 0.0f;                              // SCALE==1
  *l_out = (int)(idx < 0 ? 0 : (idx > (NLORA - 1) ? (NLORA - 1) : idx));
}

// ---------------------------------------------------------------------------
// Kernel 1: x [B][C][H][W] fp32 -> x_pad [B][C/32][66][66][32] bf16.
// ---------------------------------------------------------------------------
__global__ __launch_bounds__(256)
void pad_convert(const float* __restrict__ x, ushort_t* __restrict__ x_pad) {
  __shared__ float t[64][65];
  const int cc  = blockIdx.x;   // 64-ch group 0..4
  const int h   = blockIdx.y;   // 0..63
  const int b   = blockIdx.z;
  const int tid = threadIdx.x;
  #pragma unroll
  for (int it = 0; it < 4; ++it) {
    int idx = it * 256 + tid;               // 0..1023
    int cl = idx >> 4, w4 = (idx & 15) * 4;
    float4v v = *(const float4v*)(x +
        (((size_t)(b * CIN_ + cc * 64 + cl)) * 64 + h) * 64 + w4);
    t[cl][w4] = v[0]; t[cl][w4 + 1] = v[1];
    t[cl][w4 + 2] = v[2]; t[cl][w4 + 3] = v[3];
  }
  __syncthreads();
  #pragma unroll
  for (int it = 0; it < 4; ++it) {
    int j  = it * 256 + tid;                // 0..1023
    int cq = j & 15, wl = j >> 4;           // 4-ch group, col
    int cl = cq * 4;
    uint_t u0 = (uint_t)bf16rne(t[cl][wl])     | ((uint_t)bf16rne(t[cl + 1][wl]) << 16);
    uint_t u1 = (uint_t)bf16rne(t[cl + 2][wl]) | ((uint_t)bf16rne(t[cl + 3][wl]) << 16);
    int chunk = cc * 2 + (cl >> 5);
    uint2v u; u[0] = u0; u[1] = u1;
    *(uint2v*)(x_pad + (((size_t)(b * NCH + chunk) * 66 + (h + 1)) * 66 + (wl + 1)) * 32
               + (cl & 31)) = u;
  }
  if (h == 0) {
    #pragma unroll
    for (int s = 0; s < 2; ++s) {
      ushort_t* base = x_pad + (size_t)(b * NCH + cc * 2 + s) * XCHUNK;
      for (int g = tid; g < 528; g += 256) {            // rows 0 and 65
        int r = (g >= 264) ? 1 : 0;
        int g2 = g - r * 264;
        int col = g2 >> 2, qg = g2 & 3;
        *(uint4v*)(base + ((size_t)(r * 65) * 66 + col) * 32 + qg * 8) = (uint4v)0u;
      }
      for (int g = tid; g < 512; g += 256) {            // cols 0,65 rows 1..64
        int row = 1 + (g >> 3);
        int col = ((g >> 2) & 1) * 65;
        int qg  = g & 3;
        *(uint4v*)(base + ((size_t)row * 66 + col) * 32 + qg * 8) = (uint4v)0u;
      }
    }
  }
}

// ---------------------------------------------------------------------------
// Kernel 2a: conv_w fp32 -> wb16 [10][9][320][32] bf16 (batch-independent)
// ---------------------------------------------------------------------------
__global__ __launch_bounds__(512)
void wconv(const float* __restrict__ conv_w, ushort_t* __restrict__ wb16) {
  int idx = blockIdx.x * 512 + threadIdx.x;          // 0..921599
  int c5 = idx & 31;
  int o  = (idx >> 5) % COUT_;
  int rest = idx / (COUT_ * 32);                     // 0..89
  int tap = rest % 9, chunk = rest / 9;
  wb16[idx] = bf16rne(conv_w[((size_t)o * CIN_ + chunk * 32 + c5) * 9 + tap]);
}

// ---------------------------------------------------------------------------
// Kernel 2b: down_w fp32 -> dwn_eff [B][10][9][16][32] bf16, r>=4 -> 0,
// act folded (inactive sample => all-zero weights => down == 0).
// ---------------------------------------------------------------------------
__global__ __launch_bounds__(512)
void dwnconv(const float* __restrict__ down_w, const void* __restrict__ lora,
             ushort_t* __restrict__ dwn_eff) {
  const int b = blockIdx.x;
  int l; float act;
  lora_idx(lora, b, &l, &act);
  ushort_t* dst = dwn_eff + (size_t)b * (NCH * DCHUNK);
  const float* src = down_w + (size_t)l * (R_ * CIN_ * 9);
  for (int it = 0; it < 90; ++it) {
    int idx = it * 512 + threadIdx.x;                // 0..46079
    int c5 = idx & 31;
    int r  = (idx >> 5) & 15;
    int rest = idx >> 9;                             // 0..89
    int tap = rest % 9, chunk = rest / 9;
    float v = (r < R_) ? act * src[((size_t)(r * CIN_) + chunk * 32 + c5) * 9 + tap]
                       : 0.0f;
    dst[idx] = bf16rne(v);
  }
}

// ---------------------------------------------------------------------------
// Kernel 3: lora_down — rank-4 implicit-GEMM conv (N=16, 4 valid cols).
// Same structure/swizzle as conv_main; double-buffered, vmcnt(4) exact.
// down[b][r][h][w] fp32.
// ---------------------------------------------------------------------------
#define LXG    1360
#define LXGP   1408
#define LWG    576
#define LTOTG  2048                 // 4 * 512
#define LBUF_B (LTOTG * 16)         // 32,768 B

__global__ __launch_bounds__(512)
void lora_down(const ushort_t* __restrict__ x_pad, const ushort_t* __restrict__ dwn_eff,
               float* __restrict__ down) {
  __shared__ __align__(16) char smem[2 * LBUF_B];    // 65,536 B

  const int tid = threadIdx.x;
  const int lin = blockIdx.x;                        // 0..255
  const int b   = lin >> 4;
  const int hw  = lin & 15;
  const int h0  = (hw & 7) * 8;
  const int w0  = (hw >> 3) * 32;

  const int wv = tid >> 6;
  const int la = tid & 15;
  const int q  = (tid >> 4) & 3;

  const ushort_t* psrc[4];
  int step[4];
  #pragma unroll
  for (int r = 0; r < 4; ++r) {
    int g = r * 512 + tid;
    if (g < LXGP) {
      int gx = (g < LXG) ? g : (LXG - 1);
      int qq = gx & 3, t = gx >> 2;
      int hh = t / 34, ww = t - hh * 34;
      psrc[r] = x_pad + (size_t)b * NCH * XCHUNK
              + (((h0 + hh) * 66 + (w0 + ww)) * 32 + (qq ^ ((ww >> 1) & 3)) * 8);
      step[r] = XCHUNK;
    } else {
      int gw = g - LXGP;
      if (gw > LWG - 1) gw = LWG - 1;
      int qq = gw & 3, t2 = gw >> 2;
      int rr = t2 & 15, tap = t2 >> 4;
      psrc[r] = dwn_eff + (size_t)b * NCH * DCHUNK
              + ((tap * 16 + rr) * 32 + (qq ^ ((rr >> 1) & 3)) * 8);
      step[r] = DCHUNK;
    }
  }

  // hoisted LDS read bases (byte offsets, i/tap-invariant parts)
  const char* ax0[3]; const char* ax1[3];
  #pragma unroll
  for (int kw = 0; kw < 3; ++kw) {
    int base = (wv * 34 + la + kw) * 64 + (q ^ (((la + kw) >> 1) & 3)) * 16;
    ax0[kw] = smem + base;
    ax1[kw] = smem + LBUF_B + base;
  }
  const int bfb = 22528 + la * 64 + (q ^ ((la >> 1) & 3)) * 16;  // 1408*16
  const char* aw0 = smem + bfb;
  const char* aw1 = smem + LBUF_B + bfb;

  float4v acc[2];
  acc[0] = (float4v)0.0f; acc[1] = (float4v)0.0f;

  auto STAGE = [&](int sel) {
    ushort_t* bufb = (ushort_t*)(smem + sel * LBUF_B);
    #pragma unroll
    for (int r = 0; r < 4; ++r) {
      gld16(psrc[r], bufb + (r * 512 + wv * 64) * 8);
      psrc[r] += step[r];
    }
  };

  auto PHASE = [&](const char* axA, const char* axB, const char* axC,
                   const char* aw, bool do_stage, int sel_next) {
    __builtin_amdgcn_s_barrier();
    if (do_stage) STAGE(sel_next);
    __builtin_amdgcn_sched_barrier(0);
    if (do_stage) asm volatile("s_waitcnt vmcnt(4)" ::: "memory");
    else          asm volatile("s_waitcnt vmcnt(0)" ::: "memory");
    __builtin_amdgcn_sched_barrier(0);
    __builtin_amdgcn_s_barrier();
    __builtin_amdgcn_s_setprio(1);
    #pragma unroll
    for (int tap = 0; tap < 9; ++tap) {
      const int kh = tap / 3, kw = tap - kh * 3;
      const char* ax = (kw == 0) ? axA : ((kw == 1) ? axB : axC);
      short8 bf = *(const short8*)(aw + tap * 1024);
      #pragma unroll
      for (int i = 0; i < 2; ++i) {
        short8 af = *(const short8*)(ax + kh * 2176 + i * 1024);
        acc[i] = __builtin_amdgcn_mfma_f32_16x16x32_bf16(af, bf, acc[i], 0, 0, 0);
      }
    }
    __builtin_amdgcn_s_setprio(0);
  };

  STAGE(0);
  #pragma unroll
  for (int tp = 0; tp < 5; ++tp) {
    PHASE(ax0[0], ax0[1], ax0[2], aw0, true,    1);
    PHASE(ax1[0], ax1[1], ax1[2], aw1, tp < 4,  0);
  }

  if (la < R_) {
    #pragma unroll
    for (int i = 0; i < 2; ++i)
      *(float4v*)(down + (((size_t)(b * R_ + la) * 64 + h0 + wv) * 64)
                  + w0 + i * 16 + q * 4) = acc[i];
  }
}

// ---------------------------------------------------------------------------
// Kernel 4: main conv. Same verified geometry/pipeline as round 3 (2560
// blocks = 5 exact rounds, 8 waves, 8x32x32 tile, vmcnt(5)), PLUS:
//   * B-operand = batch-independent wb16 (L2/L3-shared across all blocks)
//   * LDS read addresses fully hoisted: Q-xor is i/n-invariant (i*16 and
//     n*16 are 0 mod 4 after >>1&3), so every ds_read = base_ptr + imm.
//   * setprio(1) around the MFMA cluster (T5).
//   * epilogue: direct stores + fused LoRA up-projection (up . down).
// ---------------------------------------------------------------------------
#define XG    1360
#define XGP   1408
#define WG    1152
#define TOTG  2560
#define BUF_B (TOTG * 16)          // 40,960 B

__global__ __launch_bounds__(512, 4)
void conv_main(const ushort_t* __restrict__ x_pad, const ushort_t* __restrict__ wb16,
               const float* __restrict__ conv_b, const float* __restrict__ up_w,
               const float* __restrict__ down, const void* __restrict__ lora,
               float* __restrict__ out) {
  __shared__ __align__(16) char smem[2 * BUF_B];     // 81,920 B

  const int tid = threadIdx.x;
  const int lin = blockIdx.x;                        // 0..2559
  const int wg  = (lin & 7) * 320 + (lin >> 3);      // XCD-bijective
  const int b   = wg / 160;
  const int rem = wg - b * 160;
  const int o0  = (rem >> 4) * 32;
  const int hw  = rem & 15;
  const int h0  = (hw & 7) * 8;
  const int w0  = (hw >> 3) * 32;

  const int wv = tid >> 6;
  const int la = tid & 15;
  const int q  = (tid >> 4) & 3;

  const ushort_t* psrc[5];
  int step[5];
  #pragma unroll
  for (int r = 0; r < 5; ++r) {
    int g = r * 512 + tid;
    if (g < XGP) {
      int gx = (g < XG) ? g : (XG - 1);
      int qq = gx & 3, t = gx >> 2;
      int hh = t / 34, ww = t - hh * 34;
      psrc[r] = x_pad + (size_t)b * NCH * XCHUNK
              + (((h0 + hh) * 66 + (w0 + ww)) * 32 + (qq ^ ((ww >> 1) & 3)) * 8);
      step[r] = XCHUNK;
    } else {
      int gw = g - XGP;
      int qq = gw & 3, t2 = gw >> 2;
      int o = t2 & 31, tap = t2 >> 5;
      psrc[r] = wb16 + ((size_t)(tap * COUT_ + o0 + o) * 32 + (qq ^ ((o >> 1) & 3)) * 8);
      step[r] = WCHUNK;
    }
  }

  // hoisted LDS read base pointers
  const char* ax0[3]; const char* ax1[3];
  #pragma unroll
  for (int kw = 0; kw < 3; ++kw) {
    int base = (wv * 34 + la + kw) * 64 + (q ^ (((la + kw) >> 1) & 3)) * 16;
    ax0[kw] = smem + base;
    ax1[kw] = smem + BUF_B + base;
  }
  const int bfb = 22528 + la * 64 + (q ^ ((la >> 1) & 3)) * 16;  // XGP*16
  const char* aw0 = smem + bfb;
  const char* aw1 = smem + BUF_B + bfb;

  float4v acc[2][2];
  #pragma unroll
  for (int i = 0; i < 2; ++i)
    #pragma unroll
    for (int n = 0; n < 2; ++n) acc[i][n] = (float4v)0.0f;

  auto STAGE = [&](int sel) {
    ushort_t* bufb = (ushort_t*)(smem + sel * BUF_B);
    #pragma unroll
    for (int r = 0; r < 5; ++r) {
      gld16(psrc[r], bufb + (r * 512 + wv * 64) * 8);
      psrc[r] += step[r];
    }
  };

  auto PHASE = [&](const char* axA, const char* axB, const char* axC,
                   const char* aw, bool do_stage, int sel_next) {
    __builtin_amdgcn_s_barrier();
    if (do_stage) STAGE(sel_next);
    __builtin_amdgcn_sched_barrier(0);
    if (do_stage) asm volatile("s_waitcnt vmcnt(5)" ::: "memory");
    else          asm volatile("s_waitcnt vmcnt(0)" ::: "memory");
    __builtin_amdgcn_sched_barrier(0);
    __builtin_amdgcn_s_barrier();
    __builtin_amdgcn_s_setprio(1);
    #pragma unroll
    for (int tap = 0; tap < 9; ++tap) {
      const int kh = tap / 3, kw = tap - kh * 3;
      const char* ax = (kw == 0) ? axA : ((kw == 1) ? axB : axC);
      short8 bf0 = *(const short8*)(aw + tap * 2048);
      short8 bf1 = *(const short8*)(aw + tap * 2048 + 1024);
      #pragma unroll
      for (int i = 0; i < 2; ++i) {
        short8 af = *(const short8*)(ax + kh * 2176 + i * 1024);
        acc[i][0] = __builtin_amdgcn_mfma_f32_16x16x32_bf16(af, bf0, acc[i][0], 0, 0, 0);
        acc[i][1] = __builtin_amdgcn_mfma_f32_16x16x32_bf16(af, bf1, acc[i][1], 0, 0, 0);
      }
    }
    __builtin_amdgcn_s_setprio(0);
  };

  STAGE(0);
  #pragma unroll
  for (int tp = 0; tp < 5; ++tp) {
    PHASE(ax0[0], ax0[1], ax0[2], aw0, true,   1);
    PHASE(ax1[0], ax1[1], ax1[2], aw1, tp < 4, 0);
  }

  // Epilogue: direct coalesced-enough stores (per o: 4 lanes x 16 B = 64 B
  // segments) + bias + fused LoRA up-projection. No LDS, no barriers.
  int l; float act;
  lora_idx(lora, b, &l, &act);
  const float* upb = up_w + (size_t)l * (COUT_ * R_);
  #pragma unroll
  for (int i = 0; i < 2; ++i) {
    float4v d[4];
    #pragma unroll
    for (int r = 0; r < 4; ++r)
      d[r] = *(const float4v*)(down + (((size_t)(b * R_ + r) * 64 + h0 + wv) * 64)
                               + w0 + i * 16 + q * 4);
    #pragma unroll
    for (int n = 0; n < 2; ++n) {
      const int o = o0 + n * 16 + la;
      float4v u = *(const float4v*)(upb + o * R_);
      float4v v = acc[i][n];
      v += conv_b[o];
      v += u[0] * d[0] + u[1] * d[1] + u[2] * d[2] + u[3] * d[3];
      *(float4v*)(out + (((size_t)(b * COUT_ + o) * 64 + h0 + wv) * 64)
                  + w0 + i * 16 + q * 4) = v;
    }
  }
}

// ---------------------------------------------------------------------------
extern "C" void kernel_launch(void* const* d_in, const int* in_sizes, int n_in,
                              void* d_out, int out_size, void* d_ws, size_t ws_size,
                              hipStream_t stream) {
  const float* x      = (const float*)d_in[0];
  const float* conv_w = (const float*)d_in[1];
  const float* conv_b = (const float*)d_in[2];
  const float* down_w = (const float*)d_in[3];
  const float* up_w   = (const float*)d_in[4];
  const void*  lora   = d_in[5];
  float* out = (float*)d_out;

  ushort_t* x_pad   = (ushort_t*)d_ws;
  ushort_t* wb16    = (ushort_t*)((char*)d_ws + WB16_OFF);
  ushort_t* dwn_eff = (ushort_t*)((char*)d_ws + DWNE_OFF);
  float*    down    = (float*)((char*)d_ws + DOWN_OFF);

  pad_convert<<<dim3(5, 64, 16), 256, 0, stream>>>(x, x_pad);
  wconv      <<<dim3(1800),      512, 0, stream>>>(conv_w, wb16);
  dwnconv    <<<dim3(16),        512, 0, stream>>>(down_w, lora, dwn_eff);
  lora_down  <<<dim3(256),       512, 0, stream>>>(x_pad, dwn_eff, down);
  conv_main  <<<dim3(2560),      512, 0, stream>>>(x_pad, wb16, conv_b, up_w,
                                                   down, lora, out);
}